// Round 5
// baseline (1730.984 us; speedup 1.0000x reference)
//
#include <hip/hip_runtime.h>
#include <math.h>

#define NNODES 20000
#define NEDGES 320000
#define NGRAPHS 200
#define K1 36
#define K2 26
#define EPB 128      // edges per block (edge kernel)
#define WPITCH 92    // LDS weight row pitch (floats): 16B-aligned rows, odd/32 bank start pattern

struct WPtrs { const float* w[6]; };

__device__ __forceinline__ float sigf(float v) { return 1.0f / (1.0f + expf(-v)); }
__device__ __forceinline__ float eluf(float v) { return v > 0.0f ? v : expm1f(v); }

// ---------------------------------------------------------------------------
// Generic fused GEMM: out[:, chunk*128+half*64 : +64] = act(A[M,128] @ Wc[128,64])
// grid.x = ceil(M/64), grid.y = nchunks*2. 64x64 output tile per workgroup.
// ---------------------------------------------------------------------------
__global__ __launch_bounds__(256) void gemm128_kernel(
    const float* __restrict__ A, WPtrs wp, float* __restrict__ out,
    int out_stride, int act)
{
    __shared__ float4 Wl[2048];   // [k][f4]: k*16 + fq   (128 x 64 floats)
    __shared__ float4 Al[2048];   // [n][k4]: n*32 + k4   (64 x 128 floats)

    const int half  = blockIdx.y & 1;
    const int chunk = blockIdx.y >> 1;
    const float4* W4 = (const float4*)(wp.w[chunk] + half * 64);

    for (int idx = threadIdx.x; idx < 2048; idx += 256) {
        int k = idx >> 4, fq = idx & 15;
        Wl[idx] = W4[k * 32 + fq];           // row stride of W is 128 floats = 32 f4
    }
    const int m0 = blockIdx.x * 64;
    const float4* A4 = (const float4*)A;
    for (int idx = threadIdx.x; idx < 2048; idx += 256) {
        int r = idx >> 5, k4 = idx & 31;
        int row = m0 + r;
        Al[idx] = (row < NNODES) ? A4[(size_t)row * 32 + k4] : make_float4(0.f, 0.f, 0.f, 0.f);
    }
    __syncthreads();

    const int fg = threadIdx.x & 15;   // feature group: f' = fg*4
    const int ng = threadIdx.x >> 4;   // node group: n = ng*4 + j

    float acc[4][4] = {};
    #pragma unroll 4
    for (int k4 = 0; k4 < 32; ++k4) {
        float4 a[4], w[4];
        #pragma unroll
        for (int j = 0; j < 4; ++j) a[j] = Al[(ng * 4 + j) * 32 + k4];
        #pragma unroll
        for (int q = 0; q < 4; ++q) w[q] = Wl[(k4 * 4 + q) * 16 + fg];
        #pragma unroll
        for (int j = 0; j < 4; ++j) {
            const float* ap = (const float*)&a[j];
            #pragma unroll
            for (int q = 0; q < 4; ++q) {
                const float* wq = (const float*)&w[q];
                #pragma unroll
                for (int jj = 0; jj < 4; ++jj)
                    acc[j][jj] = fmaf(ap[q], wq[jj], acc[j][jj]);
            }
        }
    }

    const int coff = chunk * 128 + half * 64 + fg * 4;
    #pragma unroll
    for (int j = 0; j < 4; ++j) {
        int row = m0 + ng * 4 + j;
        if (row < NNODES) {
            float4 v; float* vp = (float*)&v;
            #pragma unroll
            for (int jj = 0; jj < 4; ++jj) {
                float t = acc[j][jj];
                vp[jj] = act ? sigf(t) : t;
            }
            *(float4*)(out + (size_t)row * out_stride + coff) = v;
        }
    }
}

// ---------------------------------------------------------------------------
// Edge kernel: z = sigmoid(g)*elu(m)*(cs@W1v + (pw@W2v)*sigmoid(pw@W2vg))
// g/m reconstructed from gathered node-level products P[n][6][128].
//
// R1-R4 history: 88 per-lane weight floats can NEVER be made VGPR-resident —
// LLVM remats invariant loads regardless of launch_bounds/waves_per_eu/asm
// pins (VGPR stuck at 56-68, ~810 VALU cyc per edge vs ~230 necessary).
// R5 structure: weights staged ONCE per block into LDS (Wt[f][kk], pitch 92
// floats: rows 16B-aligned, b128 reads are 2-way-bank = conflict-free), and
// each thread processes 4 edges per group so one ds_read_b128 of weights
// feeds 16 fmacs. cs/pw rows stay wave-uniform s_loads (SMEM pipe, free
// VALU-wise). All 32 P-gathers issued before the dot-product phase.
// ---------------------------------------------------------------------------
__global__ __launch_bounds__(256)
__attribute__((amdgpu_waves_per_eu(3, 3)))
void edge_kernel(
    const float* __restrict__ P,
    const int* __restrict__ esrc, const int* __restrict__ etgt,
    const float* __restrict__ dist,
    const float* __restrict__ cs, const float* __restrict__ pw,
    const float* __restrict__ W1v, const float* __restrict__ W2v,
    const float* __restrict__ W2vg,
    float* __restrict__ x)
{
    __shared__ float Wt[128 * WPITCH];   // 47104 B -> 3 blocks/CU

    const int tid  = threadIdx.x;
    const int f    = tid & 127;
    const int esub = tid >> 7;           // wave-uniform (waves 0,1 -> 0; 2,3 -> 1)

    // ---- stage weights into LDS (once per block; ~1000 cyc, amortized over 128 edges)
    // kk 0..35  = W1v[k][f], k=kk
    // kk 36..61 = W2v[k][f], k=kk-36   (k=0..25)
    // kk 64..89 = W2vg[k][f], k=kk-64  (k=0..25)
    // kk 62,63,90,91 = pad (never read)
    for (int kk = esub; kk < WPITCH; kk += 2) {
        float v = 0.f;
        if (kk < 36)                   v = W1v[kk * 128 + f];
        else if (kk < 62)              v = W2v[(kk - 36) * 128 + f];
        else if (kk >= 64 && kk < 90)  v = W2vg[(kk - 64) * 128 + f];
        Wt[f * WPITCH + kk] = v;
    }
    __syncthreads();

    const float* Wrow = &Wt[f * WPITCH];
    const int ebase = blockIdx.x * EPB + esub * 4;

    for (int g = 0; g < EPB / 8; ++g) {
        const int e0 = __builtin_amdgcn_readfirstlane(ebase + g * 8);

        // edge metadata (uniform -> s_load)
        int sA[4], tA[4]; float dA[4];
        #pragma unroll
        for (int j = 0; j < 4; ++j) {
            sA[j] = esrc[e0 + j];
            tA[j] = etgt[e0 + j];
            dA[j] = dist[e0 + j];
        }

        // issue all 32 P-gathers up front (latency hides under the fmac phase)
        float gv[4][8];
        #pragma unroll
        for (int j = 0; j < 4; ++j) {
            const float* Ps = P + (size_t)sA[j] * 768;
            const float* Pt = P + (size_t)tA[j] * 768;
            gv[j][0] = Ps[f];        gv[j][1] = Pt[128 + f];
            gv[j][2] = Pt[256 + f];  gv[j][3] = Ps[256 + f];
            gv[j][4] = Ps[384 + f];  gv[j][5] = Pt[512 + f];
            gv[j][6] = Pt[640 + f];  gv[j][7] = Ps[640 + f];
        }

        float z1[4] = {0.f, 0.f, 0.f, 0.f};
        float za[4] = {0.f, 0.f, 0.f, 0.f};
        float zb[4] = {0.f, 0.f, 0.f, 0.f};

        // ---- z1 phase: 9 chunks of 4 k's, weights read once per chunk for 4 edges
        const float* cp0 = cs + (size_t)(e0 + 0) * K1;
        const float* cp1 = cs + (size_t)(e0 + 1) * K1;
        const float* cp2 = cs + (size_t)(e0 + 2) * K1;
        const float* cp3 = cs + (size_t)(e0 + 3) * K1;
        #pragma unroll
        for (int c = 0; c < 9; ++c) {
            float4 w = *(const float4*)(Wrow + c * 4);
            const float* wq = (const float*)&w;
            #pragma unroll
            for (int q = 0; q < 4; ++q) {
                z1[0] = fmaf(cp0[c * 4 + q], wq[q], z1[0]);
                z1[1] = fmaf(cp1[c * 4 + q], wq[q], z1[1]);
                z1[2] = fmaf(cp2[c * 4 + q], wq[q], z1[2]);
                z1[3] = fmaf(cp3[c * 4 + q], wq[q], z1[3]);
            }
        }

        // ---- za/zb phase: 6 chunks of 4 + tail of 2
        const float* qp0 = pw + (size_t)(e0 + 0) * K2;
        const float* qp1 = pw + (size_t)(e0 + 1) * K2;
        const float* qp2 = pw + (size_t)(e0 + 2) * K2;
        const float* qp3 = pw + (size_t)(e0 + 3) * K2;
        #pragma unroll
        for (int c = 0; c < 6; ++c) {
            float4 w2 = *(const float4*)(Wrow + 36 + c * 4);
            float4 wg = *(const float4*)(Wrow + 64 + c * 4);
            const float* w2q = (const float*)&w2;
            const float* wgq = (const float*)&wg;
            #pragma unroll
            for (int q = 0; q < 4; ++q) {
                float p0 = qp0[c * 4 + q], p1 = qp1[c * 4 + q];
                float p2 = qp2[c * 4 + q], p3 = qp3[c * 4 + q];
                za[0] = fmaf(p0, w2q[q], za[0]);  zb[0] = fmaf(p0, wgq[q], zb[0]);
                za[1] = fmaf(p1, w2q[q], za[1]);  zb[1] = fmaf(p1, wgq[q], zb[1]);
                za[2] = fmaf(p2, w2q[q], za[2]);  zb[2] = fmaf(p2, wgq[q], zb[2]);
                za[3] = fmaf(p3, w2q[q], za[3]);  zb[3] = fmaf(p3, wgq[q], zb[3]);
            }
        }
        {
            float2 w2t = *(const float2*)(Wrow + 60);
            float2 wgt = *(const float2*)(Wrow + 88);
            #pragma unroll
            for (int j = 0; j < 4; ++j) {
                const float* qpj = (j == 0) ? qp0 : (j == 1) ? qp1 : (j == 2) ? qp2 : qp3;
                float p24 = qpj[24], p25 = qpj[25];
                za[j] = fmaf(p24, w2t.x, fmaf(p25, w2t.y, za[j]));
                zb[j] = fmaf(p24, wgt.x, fmaf(p25, wgt.y, zb[j]));
            }
        }

        // ---- combine + scatter
        #pragma unroll
        for (int j = 0; j < 4; ++j) {
            float invd = 1.0f / dA[j];
            float gsum = gv[j][0] + gv[j][1] + (gv[j][2] - gv[j][3]) * invd;
            float msum = gv[j][4] + gv[j][5] + (gv[j][6] - gv[j][7]) * invd;
            float z = sigf(gsum) * eluf(msum) * (z1[j] + za[j] * sigf(zb[j]));
            atomicAdd(x + (size_t)sA[j] * 128 + f, z);
        }
    }
}

// ---------------------------------------------------------------------------
// Pool + psi elementwise: T[n][3][128] = [x@Wp1, x@Wp2, x@Wpsi]
// pools[g] += elu(T0)*T1 ; xout = elu(T2)
// ---------------------------------------------------------------------------
__global__ __launch_bounds__(256) void pool_psi_kernel(
    const float* __restrict__ T, const int* __restrict__ gidx,
    float* __restrict__ pools, float* __restrict__ xout)
{
    int idx = blockIdx.x * 256 + threadIdx.x;
    int n = idx >> 7, f = idx & 127;
    float h1 = eluf(T[(size_t)n * 384 + f]);
    float h2 = T[(size_t)n * 384 + 128 + f];
    atomicAdd(pools + (size_t)gidx[n] * 128 + f, h1 * h2);
    xout[(size_t)n * 128 + f] = eluf(T[(size_t)n * 384 + 256 + f]);
}

// ---------------------------------------------------------------------------
// Final head: per graph: elu(@Wlr1[128,64]) -> elu(@Wlr2[64,42]) -> @Wlr3[42,1]
// ---------------------------------------------------------------------------
__global__ __launch_bounds__(64) void final_kernel(
    const float* __restrict__ pools,
    const float* __restrict__ Wlr1, const float* __restrict__ Wlr2,
    const float* __restrict__ Wlr3, float* __restrict__ out)
{
    __shared__ float h1[64];
    __shared__ float h2[42];
    const int g = blockIdx.x;
    const int f = threadIdx.x;

    float a = 0.f;
    #pragma unroll 8
    for (int k = 0; k < 128; ++k) a = fmaf(pools[(size_t)g * 128 + k], Wlr1[k * 64 + f], a);
    h1[f] = eluf(a);
    __syncthreads();
    if (f < 42) {
        float b = 0.f;
        #pragma unroll
        for (int k = 0; k < 64; ++k) b = fmaf(h1[k], Wlr2[k * 42 + f], b);
        h2[f] = eluf(b);
    }
    __syncthreads();
    if (f == 0) {
        float c = 0.f;
        #pragma unroll
        for (int k = 0; k < 42; ++k) c = fmaf(h2[k], Wlr3[k], c);
        out[g] = c;
    }
}

__global__ void zero_kernel(float* p, int n)
{
    int i = blockIdx.x * 256 + threadIdx.x;
    if (i < n) p[i] = 0.f;
}

extern "C" void kernel_launch(void* const* d_in, const int* in_sizes, int n_in,
                              void* d_out, int out_size, void* d_ws, size_t ws_size,
                              hipStream_t stream)
{
    const float* nodes = (const float*)d_in[0];
    const int*   esrc  = (const int*)d_in[1];
    const int*   etgt  = (const int*)d_in[2];
    const float* dist  = (const float*)d_in[3];
    const int*   gidx  = (const int*)d_in[4];
    // d_in[5] = node_counts : unused (division discarded in the source)
    const float* cs    = (const float*)d_in[6];
    const float* pw    = (const float*)d_in[7];
    const float* W_emb = (const float*)d_in[8];
    const float* Wg    = (const float*)d_in[9];
    const float* Wm    = (const float*)d_in[10];
    const float* W1v   = (const float*)d_in[11];
    const float* W2v   = (const float*)d_in[12];
    const float* W2vg  = (const float*)d_in[13];
    const float* Wp1   = (const float*)d_in[14];
    const float* Wp2   = (const float*)d_in[15];
    const float* Wpsi  = (const float*)d_in[16];
    const float* Wlr1  = (const float*)d_in[17];
    const float* Wlr2  = (const float*)d_in[18];
    const float* Wlr3  = (const float*)d_in[19];
    float* outp = (float*)d_out;

    // workspace layout (floats): xA | xB | P(=T overlay) | pools
    float* xA    = (float*)d_ws;
    float* xB    = xA + (size_t)NNODES * 128;
    float* P     = xB + (size_t)NNODES * 128;
    float* pools = P + (size_t)NNODES * 768;   // total ~82 MB

    zero_kernel<<<100, 256, 0, stream>>>(pools, NGRAPHS * 128);

    // x = sigmoid(nodes @ W_emb)
    {
        WPtrs wp{}; wp.w[0] = W_emb;
        gemm128_kernel<<<dim3(313, 2), 256, 0, stream>>>(nodes, wp, xA, 128, 1);
    }

    float* xc = xA;
    float* xn = xB;
    for (int i = 0; i < 3; ++i) {
        // P = x @ [Wg0,Wg1,Wg2,Wm0,Wm1,Wm2]  (each 128x128, contiguous in Wg/Wm)
        WPtrs wp{};
        const float* Wgi = Wg + (size_t)i * 49152;
        const float* Wmi = Wm + (size_t)i * 49152;
        wp.w[0] = Wgi;          wp.w[1] = Wgi + 16384;  wp.w[2] = Wgi + 32768;
        wp.w[3] = Wmi;          wp.w[4] = Wmi + 16384;  wp.w[5] = Wmi + 32768;
        gemm128_kernel<<<dim3(313, 12), 256, 0, stream>>>(xc, wp, P, 768, 0);

        // gather/combine/scatter over edges (updates xc in place; reads only P)
        edge_kernel<<<NEDGES / EPB, 256, 0, stream>>>(P, esrc, etgt, dist, cs, pw,
            W1v + (size_t)i * (K1 * 128),
            W2v + (size_t)i * (K2 * 128),
            W2vg + (size_t)i * (K2 * 128), xc);

        // T = x @ [Wp1, Wp2, Wpsi]  (reuse P buffer)
        WPtrs wq{};
        wq.w[0] = Wp1 + (size_t)i * 16384;
        wq.w[1] = Wp2 + (size_t)i * 16384;
        wq.w[2] = Wpsi + (size_t)i * 16384;
        gemm128_kernel<<<dim3(313, 6), 256, 0, stream>>>(xc, wq, P, 384, 0);

        // pools[g] += elu(T0)*T1 ; xn = elu(T2)
        pool_psi_kernel<<<10000, 256, 0, stream>>>(P, gidx, pools, xn);

        float* tmp = xc; xc = xn; xn = tmp;
    }

    final_kernel<<<NGRAPHS, 64, 0, stream>>>(pools, Wlr1, Wlr2, Wlr3, outp);
}

// Round 6
// 1604.338 us; speedup vs baseline: 1.0789x; 1.0789x over previous
//
#include <hip/hip_runtime.h>
#include <math.h>

#define NNODES 20000
#define NEDGES 320000
#define NGRAPHS 200
#define K1 36
#define K2 26
#define EPB 128      // edges per block (edge kernel): 2 halves x 4-edge groups x 16 iters

struct WPtrs { const float* w[6]; };

__device__ __forceinline__ float sigf(float v) { return 1.0f / (1.0f + expf(-v)); }
__device__ __forceinline__ float eluf(float v) { return v > 0.0f ? v : expm1f(v); }

// ---------------------------------------------------------------------------
// Generic fused GEMM: out[:, chunk*128+half*64 : +64] = act(A[M,128] @ Wc[128,64])
// grid.x = ceil(M/64), grid.y = nchunks*2. 64x64 output tile per workgroup.
// ---------------------------------------------------------------------------
__global__ __launch_bounds__(256) void gemm128_kernel(
    const float* __restrict__ A, WPtrs wp, float* __restrict__ out,
    int out_stride, int act)
{
    __shared__ float4 Wl[2048];   // [k][f4]: k*16 + fq   (128 x 64 floats)
    __shared__ float4 Al[2048];   // [n][k4]: n*32 + k4   (64 x 128 floats)

    const int half  = blockIdx.y & 1;
    const int chunk = blockIdx.y >> 1;
    const float4* W4 = (const float4*)(wp.w[chunk] + half * 64);

    for (int idx = threadIdx.x; idx < 2048; idx += 256) {
        int k = idx >> 4, fq = idx & 15;
        Wl[idx] = W4[k * 32 + fq];           // row stride of W is 128 floats = 32 f4
    }
    const int m0 = blockIdx.x * 64;
    const float4* A4 = (const float4*)A;
    for (int idx = threadIdx.x; idx < 2048; idx += 256) {
        int r = idx >> 5, k4 = idx & 31;
        int row = m0 + r;
        Al[idx] = (row < NNODES) ? A4[(size_t)row * 32 + k4] : make_float4(0.f, 0.f, 0.f, 0.f);
    }
    __syncthreads();

    const int fg = threadIdx.x & 15;   // feature group: f' = fg*4
    const int ng = threadIdx.x >> 4;   // node group: n = ng*4 + j

    float acc[4][4] = {};
    #pragma unroll 4
    for (int k4 = 0; k4 < 32; ++k4) {
        float4 a[4], w[4];
        #pragma unroll
        for (int j = 0; j < 4; ++j) a[j] = Al[(ng * 4 + j) * 32 + k4];
        #pragma unroll
        for (int q = 0; q < 4; ++q) w[q] = Wl[(k4 * 4 + q) * 16 + fg];
        #pragma unroll
        for (int j = 0; j < 4; ++j) {
            const float* ap = (const float*)&a[j];
            #pragma unroll
            for (int q = 0; q < 4; ++q) {
                const float* wq = (const float*)&w[q];
                #pragma unroll
                for (int jj = 0; jj < 4; ++jj)
                    acc[j][jj] = fmaf(ap[q], wq[jj], acc[j][jj]);
            }
        }
    }

    const int coff = chunk * 128 + half * 64 + fg * 4;
    #pragma unroll
    for (int j = 0; j < 4; ++j) {
        int row = m0 + ng * 4 + j;
        if (row < NNODES) {
            float4 v; float* vp = (float*)&v;
            #pragma unroll
            for (int jj = 0; jj < 4; ++jj) {
                float t = acc[j][jj];
                vp[jj] = act ? sigf(t) : t;
            }
            *(float4*)(out + (size_t)row * out_stride + coff) = v;
        }
    }
}

// ---------------------------------------------------------------------------
// Edge kernel: z = sigmoid(g)*elu(m)*(cs@W1v + (pw@W2v)*sigmoid(pw@W2vg))
// g/m reconstructed from gathered node-level products P[n][6][128].
//
// History:
//  R1-R4: 88 per-lane weight floats can NEVER be made VGPR-resident — LLVM
//    remats the invariant loads regardless of launch_bounds / waves_per_eu /
//    asm pins (VGPR stuck 56-68; ~810 VALU cyc/edge vs ~230 necessary).
//  R5: LDS-staged weights with pitch 92 (28 mod 32, gcd 4) -> 8-way bank
//    conflicts, 2.84e6 SQ_LDS_BANK_CONFLICT, 293->460us. REVERTED.
//  R6: accept the per-iteration VMEM weight reload (it's what the compiler
//    emits anyway; coalesced, L1/L2-hot) but amortize it over FOUR edges per
//    iteration: 88 loads feed 352 fmacs (~220 cyc/edge). cs/pw/meta rows are
//    readfirstlane-uniform -> s_load (SMEM pipe, no VALU cost).
// ---------------------------------------------------------------------------
__global__ __launch_bounds__(256) void edge_kernel(
    const float* __restrict__ P,
    const int* __restrict__ esrc, const int* __restrict__ etgt,
    const float* __restrict__ dist,
    const float* __restrict__ cs, const float* __restrict__ pw,
    const float* __restrict__ W1v, const float* __restrict__ W2v,
    const float* __restrict__ W2vg,
    float* __restrict__ x)
{
    const int f    = threadIdx.x & 127;
    const int half = threadIdx.x >> 7;           // wave-uniform

    const int ebase = blockIdx.x * EPB + half * 4;

    for (int it = 0; it < EPB / 8; ++it) {
        const int e0 = __builtin_amdgcn_readfirstlane(ebase + it * 8);

        // edge metadata (uniform -> s_load)
        int sA[4], tA[4]; float dA[4];
        #pragma unroll
        for (int j = 0; j < 4; ++j) {
            sA[j] = esrc[e0 + j];
            tA[j] = etgt[e0 + j];
            dA[j] = dist[e0 + j];
        }

        // issue all 32 P-gathers up front (latency hides under the fmac phase)
        float gv[4][8];
        #pragma unroll
        for (int j = 0; j < 4; ++j) {
            const float* Ps = P + (size_t)sA[j] * 768;
            const float* Pt = P + (size_t)tA[j] * 768;
            gv[j][0] = Ps[f];        gv[j][1] = Pt[128 + f];
            gv[j][2] = Pt[256 + f];  gv[j][3] = Ps[256 + f];
            gv[j][4] = Ps[384 + f];  gv[j][5] = Pt[512 + f];
            gv[j][6] = Pt[640 + f];  gv[j][7] = Ps[640 + f];
        }

        // dot products: each weight load (coalesced, cache-hot) feeds 4 edges
        const float* cp0 = cs + (size_t)(e0 + 0) * K1;
        const float* cp1 = cs + (size_t)(e0 + 1) * K1;
        const float* cp2 = cs + (size_t)(e0 + 2) * K1;
        const float* cp3 = cs + (size_t)(e0 + 3) * K1;
        float z1[4] = {0.f, 0.f, 0.f, 0.f};
        #pragma unroll
        for (int k = 0; k < K1; ++k) {
            float wk = W1v[k * 128 + f];
            z1[0] = fmaf(cp0[k], wk, z1[0]);
            z1[1] = fmaf(cp1[k], wk, z1[1]);
            z1[2] = fmaf(cp2[k], wk, z1[2]);
            z1[3] = fmaf(cp3[k], wk, z1[3]);
        }

        const float* qp0 = pw + (size_t)(e0 + 0) * K2;
        const float* qp1 = pw + (size_t)(e0 + 1) * K2;
        const float* qp2 = pw + (size_t)(e0 + 2) * K2;
        const float* qp3 = pw + (size_t)(e0 + 3) * K2;
        float za[4] = {0.f, 0.f, 0.f, 0.f};
        float zb[4] = {0.f, 0.f, 0.f, 0.f};
        #pragma unroll
        for (int k = 0; k < K2; ++k) {
            float w2k = W2v[k * 128 + f];
            float wgk = W2vg[k * 128 + f];
            float p0 = qp0[k], p1 = qp1[k], p2 = qp2[k], p3 = qp3[k];
            za[0] = fmaf(p0, w2k, za[0]);  zb[0] = fmaf(p0, wgk, zb[0]);
            za[1] = fmaf(p1, w2k, za[1]);  zb[1] = fmaf(p1, wgk, zb[1]);
            za[2] = fmaf(p2, w2k, za[2]);  zb[2] = fmaf(p2, wgk, zb[2]);
            za[3] = fmaf(p3, w2k, za[3]);  zb[3] = fmaf(p3, wgk, zb[3]);
        }

        // combine + scatter
        #pragma unroll
        for (int j = 0; j < 4; ++j) {
            float invd = 1.0f / dA[j];
            float gsum = gv[j][0] + gv[j][1] + (gv[j][2] - gv[j][3]) * invd;
            float msum = gv[j][4] + gv[j][5] + (gv[j][6] - gv[j][7]) * invd;
            float z = sigf(gsum) * eluf(msum) * (z1[j] + za[j] * sigf(zb[j]));
            atomicAdd(x + (size_t)sA[j] * 128 + f, z);
        }
    }
}

// ---------------------------------------------------------------------------
// Pool + psi elementwise: T[n][3][128] = [x@Wp1, x@Wp2, x@Wpsi]
// pools[g] += elu(T0)*T1 ; xout = elu(T2)
// ---------------------------------------------------------------------------
__global__ __launch_bounds__(256) void pool_psi_kernel(
    const float* __restrict__ T, const int* __restrict__ gidx,
    float* __restrict__ pools, float* __restrict__ xout)
{
    int idx = blockIdx.x * 256 + threadIdx.x;
    int n = idx >> 7, f = idx & 127;
    float h1 = eluf(T[(size_t)n * 384 + f]);
    float h2 = T[(size_t)n * 384 + 128 + f];
    atomicAdd(pools + (size_t)gidx[n] * 128 + f, h1 * h2);
    xout[(size_t)n * 128 + f] = eluf(T[(size_t)n * 384 + 256 + f]);
}

// ---------------------------------------------------------------------------
// Final head: per graph: elu(@Wlr1[128,64]) -> elu(@Wlr2[64,42]) -> @Wlr3[42,1]
// ---------------------------------------------------------------------------
__global__ __launch_bounds__(64) void final_kernel(
    const float* __restrict__ pools,
    const float* __restrict__ Wlr1, const float* __restrict__ Wlr2,
    const float* __restrict__ Wlr3, float* __restrict__ out)
{
    __shared__ float h1[64];
    __shared__ float h2[42];
    const int g = blockIdx.x;
    const int f = threadIdx.x;

    float a = 0.f;
    #pragma unroll 8
    for (int k = 0; k < 128; ++k) a = fmaf(pools[(size_t)g * 128 + k], Wlr1[k * 64 + f], a);
    h1[f] = eluf(a);
    __syncthreads();
    if (f < 42) {
        float b = 0.f;
        #pragma unroll
        for (int k = 0; k < 64; ++k) b = fmaf(h1[k], Wlr2[k * 42 + f], b);
        h2[f] = eluf(b);
    }
    __syncthreads();
    if (f == 0) {
        float c = 0.f;
        #pragma unroll
        for (int k = 0; k < 42; ++k) c = fmaf(h2[k], Wlr3[k], c);
        out[g] = c;
    }
}

__global__ void zero_kernel(float* p, int n)
{
    int i = blockIdx.x * 256 + threadIdx.x;
    if (i < n) p[i] = 0.f;
}

extern "C" void kernel_launch(void* const* d_in, const int* in_sizes, int n_in,
                              void* d_out, int out_size, void* d_ws, size_t ws_size,
                              hipStream_t stream)
{
    const float* nodes = (const float*)d_in[0];
    const int*   esrc  = (const int*)d_in[1];
    const int*   etgt  = (const int*)d_in[2];
    const float* dist  = (const float*)d_in[3];
    const int*   gidx  = (const int*)d_in[4];
    // d_in[5] = node_counts : unused (division discarded in the source)
    const float* cs    = (const float*)d_in[6];
    const float* pw    = (const float*)d_in[7];
    const float* W_emb = (const float*)d_in[8];
    const float* Wg    = (const float*)d_in[9];
    const float* Wm    = (const float*)d_in[10];
    const float* W1v   = (const float*)d_in[11];
    const float* W2v   = (const float*)d_in[12];
    const float* W2vg  = (const float*)d_in[13];
    const float* Wp1   = (const float*)d_in[14];
    const float* Wp2   = (const float*)d_in[15];
    const float* Wpsi  = (const float*)d_in[16];
    const float* Wlr1  = (const float*)d_in[17];
    const float* Wlr2  = (const float*)d_in[18];
    const float* Wlr3  = (const float*)d_in[19];
    float* outp = (float*)d_out;

    // workspace layout (floats): xA | xB | P(=T overlay) | pools
    float* xA    = (float*)d_ws;
    float* xB    = xA + (size_t)NNODES * 128;
    float* P     = xB + (size_t)NNODES * 128;
    float* pools = P + (size_t)NNODES * 768;   // total ~82 MB

    zero_kernel<<<100, 256, 0, stream>>>(pools, NGRAPHS * 128);

    // x = sigmoid(nodes @ W_emb)
    {
        WPtrs wp{}; wp.w[0] = W_emb;
        gemm128_kernel<<<dim3(313, 2), 256, 0, stream>>>(nodes, wp, xA, 128, 1);
    }

    float* xc = xA;
    float* xn = xB;
    for (int i = 0; i < 3; ++i) {
        // P = x @ [Wg0,Wg1,Wg2,Wm0,Wm1,Wm2]  (each 128x128, contiguous in Wg/Wm)
        WPtrs wp{};
        const float* Wgi = Wg + (size_t)i * 49152;
        const float* Wmi = Wm + (size_t)i * 49152;
        wp.w[0] = Wgi;          wp.w[1] = Wgi + 16384;  wp.w[2] = Wgi + 32768;
        wp.w[3] = Wmi;          wp.w[4] = Wmi + 16384;  wp.w[5] = Wmi + 32768;
        gemm128_kernel<<<dim3(313, 12), 256, 0, stream>>>(xc, wp, P, 768, 0);

        // gather/combine/scatter over edges (updates xc in place; reads only P)
        edge_kernel<<<NEDGES / EPB, 256, 0, stream>>>(P, esrc, etgt, dist, cs, pw,
            W1v + (size_t)i * (K1 * 128),
            W2v + (size_t)i * (K2 * 128),
            W2vg + (size_t)i * (K2 * 128), xc);

        // T = x @ [Wp1, Wp2, Wpsi]  (reuse P buffer)
        WPtrs wq{};
        wq.w[0] = Wp1 + (size_t)i * 16384;
        wq.w[1] = Wp2 + (size_t)i * 16384;
        wq.w[2] = Wpsi + (size_t)i * 16384;
        gemm128_kernel<<<dim3(313, 6), 256, 0, stream>>>(xc, wq, P, 384, 0);

        // pools[g] += elu(T0)*T1 ; xn = elu(T2)
        pool_psi_kernel<<<10000, 256, 0, stream>>>(P, gidx, pools, xn);

        float* tmp = xc; xc = xn; xn = tmp;
    }

    final_kernel<<<NGRAPHS, 64, 0, stream>>>(pools, Wlr1, Wlr2, Wlr3, outp);
}

// Round 7
// 1491.296 us; speedup vs baseline: 1.1607x; 1.0758x over previous
//
#include <hip/hip_runtime.h>
#include <math.h>

#define NNODES 20000
#define NEDGES 320000
#define NGRAPHS 200
#define K1 36
#define K2 26
#define EPB 64       // edges per block (edge kernel): 4 waves x 16 iters

struct WPtrs { const float* w[6]; };

__device__ __forceinline__ float sigf(float v) { return 1.0f / (1.0f + __expf(-v)); }
__device__ __forceinline__ float eluf(float v) { return v > 0.0f ? v : __expf(v) - 1.0f; }

// ---------------------------------------------------------------------------
// Generic fused GEMM: out[:, chunk*128+half*64 : +64] = act(A[M,128] @ Wc[128,64])
// grid.x = ceil(M/64), grid.y = nchunks*2. 64x64 output tile per workgroup.
// ---------------------------------------------------------------------------
__global__ __launch_bounds__(256) void gemm128_kernel(
    const float* __restrict__ A, WPtrs wp, float* __restrict__ out,
    int out_stride, int act)
{
    __shared__ float4 Wl[2048];   // [k][f4]: k*16 + fq   (128 x 64 floats)
    __shared__ float4 Al[2048];   // [n][k4]: n*32 + k4   (64 x 128 floats)

    const int half  = blockIdx.y & 1;
    const int chunk = blockIdx.y >> 1;
    const float4* W4 = (const float4*)(wp.w[chunk] + half * 64);

    for (int idx = threadIdx.x; idx < 2048; idx += 256) {
        int k = idx >> 4, fq = idx & 15;
        Wl[idx] = W4[k * 32 + fq];           // row stride of W is 128 floats = 32 f4
    }
    const int m0 = blockIdx.x * 64;
    const float4* A4 = (const float4*)A;
    for (int idx = threadIdx.x; idx < 2048; idx += 256) {
        int r = idx >> 5, k4 = idx & 31;
        int row = m0 + r;
        Al[idx] = (row < NNODES) ? A4[(size_t)row * 32 + k4] : make_float4(0.f, 0.f, 0.f, 0.f);
    }
    __syncthreads();

    const int fg = threadIdx.x & 15;   // feature group: f' = fg*4
    const int ng = threadIdx.x >> 4;   // node group: n = ng*4 + j

    float acc[4][4] = {};
    #pragma unroll 4
    for (int k4 = 0; k4 < 32; ++k4) {
        float4 a[4], w[4];
        #pragma unroll
        for (int j = 0; j < 4; ++j) a[j] = Al[(ng * 4 + j) * 32 + k4];
        #pragma unroll
        for (int q = 0; q < 4; ++q) w[q] = Wl[(k4 * 4 + q) * 16 + fg];
        #pragma unroll
        for (int j = 0; j < 4; ++j) {
            const float* ap = (const float*)&a[j];
            #pragma unroll
            for (int q = 0; q < 4; ++q) {
                const float* wq = (const float*)&w[q];
                #pragma unroll
                for (int jj = 0; jj < 4; ++jj)
                    acc[j][jj] = fmaf(ap[q], wq[jj], acc[j][jj]);
            }
        }
    }

    const int coff = chunk * 128 + half * 64 + fg * 4;
    #pragma unroll
    for (int j = 0; j < 4; ++j) {
        int row = m0 + ng * 4 + j;
        if (row < NNODES) {
            float4 v; float* vp = (float*)&v;
            #pragma unroll
            for (int jj = 0; jj < 4; ++jj) {
                float t = acc[j][jj];
                vp[jj] = act ? sigf(t) : t;
            }
            *(float4*)(out + (size_t)row * out_stride + coff) = v;
        }
    }
}

// ---------------------------------------------------------------------------
// Edge kernel: z = sigmoid(g)*elu(m)*(cs@W1v + (pw@W2v)*sigmoid(pw@W2vg))
// g/m reconstructed from gathered node-level products P[n][6][128].
//
// History:
//  R1-R4: 88 per-lane loop-invariant weight floats can never be made VGPR-
//    resident — LLVM remats invariant loads (VGPR stuck 56-68).
//  R5: LDS weights, pitch 92 -> 8-way bank conflicts (2.84e6), 460us. REVERTED.
//  R6: 4-edge amortization -> gv[4][8] prefetch spilled to scratch (VGPR 72,
//    occupancy 30%, ~1030 cyc/edge). REVERTED.
//  R7: ONE WAVE PER EDGE, TWO FEATURES PER LANE (f=2*lane,2*lane+1):
//    - weight loads dwordx2: 88 loads feed 176 fmacs (width amortization,
//      no extra live state -> nothing to spill)
//    - gathers dwordx2: 8 per edge-wave (was 16 per 2-wave pair)
//    - cs/pw s_loads + meta per edge halved; wave-edges halved (320k)
//    - __expf-based sigmoid/elu (v_exp_f32, ~5 inst vs libm ~15-20)
// ---------------------------------------------------------------------------
__global__ __launch_bounds__(256) void edge_kernel(
    const float* __restrict__ P,
    const int* __restrict__ esrc, const int* __restrict__ etgt,
    const float* __restrict__ dist,
    const float* __restrict__ cs, const float* __restrict__ pw,
    const float* __restrict__ W1v, const float* __restrict__ W2v,
    const float* __restrict__ W2vg,
    float* __restrict__ x)
{
    const int lane = threadIdx.x & 63;
    const int wid  = threadIdx.x >> 6;     // wave id 0..3
    const int f2   = lane * 2;             // features f2, f2+1

    const int ebase = blockIdx.x * EPB + wid;

    for (int it = 0; it < EPB / 4; ++it) {
        const int e = __builtin_amdgcn_readfirstlane(ebase + it * 4);
        const int s = esrc[e];
        const int t = etgt[e];
        const float d = dist[e];
        const float* csr = cs + (size_t)e * K1;
        const float* pwr = pw + (size_t)e * K2;

        // dot products: weight dwordx2 per k feeds 2 features; cs/pw are SGPR
        float z1x = 0.f, z1y = 0.f;
        #pragma unroll
        for (int k = 0; k < K1; ++k) {
            float2 w = *(const float2*)(W1v + k * 128 + f2);
            float c = csr[k];
            z1x = fmaf(c, w.x, z1x);
            z1y = fmaf(c, w.y, z1y);
        }
        float zax = 0.f, zay = 0.f, zbx = 0.f, zby = 0.f;
        #pragma unroll
        for (int k = 0; k < K2; ++k) {
            float2 w2 = *(const float2*)(W2v + k * 128 + f2);
            float2 wg = *(const float2*)(W2vg + k * 128 + f2);
            float p = pwr[k];
            zax = fmaf(p, w2.x, zax);  zay = fmaf(p, w2.y, zay);
            zbx = fmaf(p, wg.x, zbx);  zby = fmaf(p, wg.y, zby);
        }

        // 8 gathers (dwordx2), issued after dots so live range is short
        const float* Ps = P + (size_t)s * 768 + f2;
        const float* Pt = P + (size_t)t * 768 + f2;
        float2 a0 = *(const float2*)(Ps);
        float2 a1 = *(const float2*)(Pt + 128);
        float2 a2 = *(const float2*)(Pt + 256);
        float2 a3 = *(const float2*)(Ps + 256);
        float2 b0 = *(const float2*)(Ps + 384);
        float2 b1 = *(const float2*)(Pt + 512);
        float2 b2 = *(const float2*)(Pt + 640);
        float2 b3 = *(const float2*)(Ps + 640);

        const float invd = 1.0f / d;
        float gx = a0.x + a1.x + (a2.x - a3.x) * invd;
        float gy = a0.y + a1.y + (a2.y - a3.y) * invd;
        float mx = b0.x + b1.x + (b2.x - b3.x) * invd;
        float my = b0.y + b1.y + (b2.y - b3.y) * invd;
        float zx = sigf(gx) * eluf(mx) * (z1x + zax * sigf(zbx));
        float zy = sigf(gy) * eluf(my) * (z1y + zay * sigf(zby));

        float* xp = x + (size_t)s * 128 + f2;
        atomicAdd(xp, zx);
        atomicAdd(xp + 1, zy);
    }
}

// ---------------------------------------------------------------------------
// Pool + psi elementwise: T[n][3][128] = [x@Wp1, x@Wp2, x@Wpsi]
// pools[g] += elu(T0)*T1 ; xout = elu(T2)
// ---------------------------------------------------------------------------
__global__ __launch_bounds__(256) void pool_psi_kernel(
    const float* __restrict__ T, const int* __restrict__ gidx,
    float* __restrict__ pools, float* __restrict__ xout)
{
    int idx = blockIdx.x * 256 + threadIdx.x;
    int n = idx >> 7, f = idx & 127;
    float h1 = eluf(T[(size_t)n * 384 + f]);
    float h2 = T[(size_t)n * 384 + 128 + f];
    atomicAdd(pools + (size_t)gidx[n] * 128 + f, h1 * h2);
    xout[(size_t)n * 128 + f] = eluf(T[(size_t)n * 384 + 256 + f]);
}

// ---------------------------------------------------------------------------
// Final head: per graph: elu(@Wlr1[128,64]) -> elu(@Wlr2[64,42]) -> @Wlr3[42,1]
// ---------------------------------------------------------------------------
__global__ __launch_bounds__(64) void final_kernel(
    const float* __restrict__ pools,
    const float* __restrict__ Wlr1, const float* __restrict__ Wlr2,
    const float* __restrict__ Wlr3, float* __restrict__ out)
{
    __shared__ float h1[64];
    __shared__ float h2[42];
    const int g = blockIdx.x;
    const int f = threadIdx.x;

    float a = 0.f;
    #pragma unroll 8
    for (int k = 0; k < 128; ++k) a = fmaf(pools[(size_t)g * 128 + k], Wlr1[k * 64 + f], a);
    h1[f] = eluf(a);
    __syncthreads();
    if (f < 42) {
        float b = 0.f;
        #pragma unroll
        for (int k = 0; k < 64; ++k) b = fmaf(h1[k], Wlr2[k * 42 + f], b);
        h2[f] = eluf(b);
    }
    __syncthreads();
    if (f == 0) {
        float c = 0.f;
        #pragma unroll
        for (int k = 0; k < 42; ++k) c = fmaf(h2[k], Wlr3[k], c);
        out[g] = c;
    }
}

__global__ void zero_kernel(float* p, int n)
{
    int i = blockIdx.x * 256 + threadIdx.x;
    if (i < n) p[i] = 0.f;
}

extern "C" void kernel_launch(void* const* d_in, const int* in_sizes, int n_in,
                              void* d_out, int out_size, void* d_ws, size_t ws_size,
                              hipStream_t stream)
{
    const float* nodes = (const float*)d_in[0];
    const int*   esrc  = (const int*)d_in[1];
    const int*   etgt  = (const int*)d_in[2];
    const float* dist  = (const float*)d_in[3];
    const int*   gidx  = (const int*)d_in[4];
    // d_in[5] = node_counts : unused (division discarded in the source)
    const float* cs    = (const float*)d_in[6];
    const float* pw    = (const float*)d_in[7];
    const float* W_emb = (const float*)d_in[8];
    const float* Wg    = (const float*)d_in[9];
    const float* Wm    = (const float*)d_in[10];
    const float* W1v   = (const float*)d_in[11];
    const float* W2v   = (const float*)d_in[12];
    const float* W2vg  = (const float*)d_in[13];
    const float* Wp1   = (const float*)d_in[14];
    const float* Wp2   = (const float*)d_in[15];
    const float* Wpsi  = (const float*)d_in[16];
    const float* Wlr1  = (const float*)d_in[17];
    const float* Wlr2  = (const float*)d_in[18];
    const float* Wlr3  = (const float*)d_in[19];
    float* outp = (float*)d_out;

    // workspace layout (floats): xA | xB | P(=T overlay) | pools
    float* xA    = (float*)d_ws;
    float* xB    = xA + (size_t)NNODES * 128;
    float* P     = xB + (size_t)NNODES * 128;
    float* pools = P + (size_t)NNODES * 768;   // total ~82 MB

    zero_kernel<<<100, 256, 0, stream>>>(pools, NGRAPHS * 128);

    // x = sigmoid(nodes @ W_emb)
    {
        WPtrs wp{}; wp.w[0] = W_emb;
        gemm128_kernel<<<dim3(313, 2), 256, 0, stream>>>(nodes, wp, xA, 128, 1);
    }

    float* xc = xA;
    float* xn = xB;
    for (int i = 0; i < 3; ++i) {
        // P = x @ [Wg0,Wg1,Wg2,Wm0,Wm1,Wm2]  (each 128x128, contiguous in Wg/Wm)
        WPtrs wp{};
        const float* Wgi = Wg + (size_t)i * 49152;
        const float* Wmi = Wm + (size_t)i * 49152;
        wp.w[0] = Wgi;          wp.w[1] = Wgi + 16384;  wp.w[2] = Wgi + 32768;
        wp.w[3] = Wmi;          wp.w[4] = Wmi + 16384;  wp.w[5] = Wmi + 32768;
        gemm128_kernel<<<dim3(313, 12), 256, 0, stream>>>(xc, wp, P, 768, 0);

        // gather/combine/scatter over edges (updates xc in place; reads only P)
        edge_kernel<<<NEDGES / EPB, 256, 0, stream>>>(P, esrc, etgt, dist, cs, pw,
            W1v + (size_t)i * (K1 * 128),
            W2v + (size_t)i * (K2 * 128),
            W2vg + (size_t)i * (K2 * 128), xc);

        // T = x @ [Wp1, Wp2, Wpsi]  (reuse P buffer)
        WPtrs wq{};
        wq.w[0] = Wp1 + (size_t)i * 16384;
        wq.w[1] = Wp2 + (size_t)i * 16384;
        wq.w[2] = Wpsi + (size_t)i * 16384;
        gemm128_kernel<<<dim3(313, 6), 256, 0, stream>>>(xc, wq, P, 384, 0);

        // pools[g] += elu(T0)*T1 ; xn = elu(T2)
        pool_psi_kernel<<<10000, 256, 0, stream>>>(P, gidx, pools, xn);

        float* tmp = xc; xc = xn; xn = tmp;
    }

    final_kernel<<<NGRAPHS, 64, 0, stream>>>(pools, Wlr1, Wlr2, Wlr3, outp);
}